// Round 7
// baseline (160.470 us; speedup 1.0000x reference)
//
#include <hip/hip_runtime.h>
#include <math.h>

// Dims (fixed by the problem)
#define B_SZ 2
#define L_SZ 384
#define D_SZ 384
#define S_SZ 384
#define BLK_ELEMS (L_SZ * D_SZ)        // 147456 per batch
#define TOT_ELEMS (B_SZ * L_SZ * D_SZ) // 294912
#define LOG2E 1.4426950408889634f

typedef __attribute__((ext_vector_type(8))) short bf16x8;
typedef __attribute__((ext_vector_type(4))) float f32x4;

__device__ __forceinline__ float fexp2(float x) {
  return __builtin_amdgcn_exp2f(x);
}
__device__ __forceinline__ float softplus_f(float z) {
  return (z > 20.f) ? z : log1pf(__expf(z));
}
__device__ __forceinline__ unsigned short f2bf(float f) {  // RNE f32->bf16
  unsigned int u = __float_as_uint(f);
  return (unsigned short)((u + 0x7FFFu + ((u >> 16) & 1u)) >> 16);
}
// Compiler scheduling fence (stops prefetch-load sinking; R4-R6 lesson).
#define PIPELINE_FENCE() asm volatile("" ::: "memory")

// ---------------------------------------------------------------------------
// Convert x, dt_w, B_w, C_w to bf16. Block-segmented so no per-thread branch.
// ---------------------------------------------------------------------------
__global__ __launch_bounds__(256) void cvt_bf16_kernel(
    const float* __restrict__ x, const float* __restrict__ dt_w,
    const float* __restrict__ B_w, const float* __restrict__ C_w,
    unsigned short* __restrict__ xbf, unsigned short* __restrict__ dtwbf,
    unsigned short* __restrict__ Bwbf, unsigned short* __restrict__ Cwbf) {
  const int blk = blockIdx.x;
  const float* src;
  unsigned short* dst;
  int base;
  if (blk < 288) { src = x; dst = xbf; base = blk; }
  else if (blk < 432) { src = dt_w; dst = dtwbf; base = blk - 288; }
  else if (blk < 576) { src = B_w; dst = Bwbf; base = blk - 432; }
  else { src = C_w; dst = Cwbf; base = blk - 576; }
  const int idx = base * 1024 + threadIdx.x * 4;
  const float4 v = *(const float4*)(src + idx);
  ushort4 o;
  o.x = f2bf(v.x); o.y = f2bf(v.y); o.z = f2bf(v.z); o.w = f2bf(v.w);
  *(ushort4*)(dst + idx) = o;
}

// ---------------------------------------------------------------------------
// Barrier-free dual MFMA NT-GEMM (R6 structure). One wave per 16x16 tile,
// 36 independent 16-B fragment loads (144 VGPRs live) then 24 MFMAs.
// R6 BUG: __launch_bounds__(256) let the compiler target 64 VGPRs ->
// fragment SPILL to scratch. (256,2) grants a 256-VGPR budget: the burst
// stays in registers; 2 waves/EU is ample for one L2 round-trip burst.
// ---------------------------------------------------------------------------
template <int MODE>
__global__ __launch_bounds__(256, 2) void mfma_dual_gemm(
    const unsigned short* __restrict__ Abf,
    const unsigned short* __restrict__ W1bf,
    const unsigned short* __restrict__ W2bf,
    const float* __restrict__ bias,
    float* __restrict__ O1, void* __restrict__ O2v) {
  const int wid = ((blockIdx.x << 8) + (int)threadIdx.x) >> 6;  // 0..1151
  const int mt = wid / 24;        // 0..47
  const int nt = wid - mt * 24;   // 0..23
  const int lane = threadIdx.x & 63;
  const int rc = lane & 15;
  const int quad = lane >> 4;

  const unsigned short* ap = Abf + (mt * 16 + rc) * 384 + quad * 8;
  const unsigned short* w1p = W1bf + (nt * 16 + rc) * 384 + quad * 8;
  const unsigned short* w2p = W2bf + (nt * 16 + rc) * 384 + quad * 8;

  bf16x8 af[12], w1f[12], w2f[12];
#pragma unroll
  for (int kt = 0; kt < 12; ++kt) {
    af[kt] = *(const bf16x8*)(ap + kt * 32);
    w1f[kt] = *(const bf16x8*)(w1p + kt * 32);
    w2f[kt] = *(const bf16x8*)(w2p + kt * 32);
  }
  PIPELINE_FENCE();
  f32x4 acc1 = {0.f, 0.f, 0.f, 0.f};
  f32x4 acc2 = {0.f, 0.f, 0.f, 0.f};
#pragma unroll
  for (int kt = 0; kt < 12; ++kt) {
    acc1 = __builtin_amdgcn_mfma_f32_16x16x32_bf16(af[kt], w1f[kt], acc1, 0, 0, 0);
    acc2 = __builtin_amdgcn_mfma_f32_16x16x32_bf16(af[kt], w2f[kt], acc2, 0, 0, 0);
  }
  const int col = nt * 16 + rc;
  const int row0 = mt * 16 + quad * 4;
  if constexpr (MODE == 1) {
    unsigned short* O2 = (unsigned short*)O2v;
    const float bb = bias[col];
#pragma unroll
    for (int r = 0; r < 4; ++r) {
      O1[(row0 + r) * 384 + col] = softplus_f(acc1[r] + bb);
      O2[(row0 + r) * 384 + col] = f2bf(acc2[r]);
    }
  } else {
    float* O2 = (float*)O2v;
#pragma unroll
    for (int r = 0; r < 4; ++r) {
      O1[(row0 + r) * 384 + col] = acc1[r];
      O2[(row0 + r) * 384 + col] = acc2[r];
    }
  }
}

// ---------------------------------------------------------------------------
// Conv + SiLU + transpose: computes u[b,l,i] (coalesced) and writes
// dt_t[b,i,l], dtu_t[b,i,l] via 32x32 LDS transpose so the scan reads
// dt/dtu as contiguous rows (R6: strided 4B loads = 16x line over-fetch).
// Grid (12,12,2), block (32,8).
// ---------------------------------------------------------------------------
__global__ __launch_bounds__(256) void conv_tr_kernel(
    const float* __restrict__ x, const float* __restrict__ cw,
    const float* __restrict__ cb, const float* __restrict__ dt,
    float* __restrict__ u, float* __restrict__ dt_t,
    float* __restrict__ dtu_t) {
  __shared__ float Tdt[32][33];
  __shared__ float Tdu[32][33];
  const int tx = threadIdx.x;   // 0..31
  const int ty = threadIdx.y;   // 0..7
  const int b = blockIdx.z;
  const int i0 = blockIdx.y * 32;
  const int l0 = blockIdx.x * 32;
  const int gi = i0 + tx;
  const float cbv = cb[gi];
  const float cw0 = cw[gi * 4 + 0], cw1 = cw[gi * 4 + 1];
  const float cw2 = cw[gi * 4 + 2], cw3 = cw[gi * 4 + 3];
#pragma unroll
  for (int r = 0; r < 4; ++r) {
    const int l = l0 + ty + 8 * r;
    float acc = cbv;
    const float x3 = x[(b * L_SZ + l) * D_SZ + gi];
    const float x2 = (l >= 1) ? x[(b * L_SZ + l - 1) * D_SZ + gi] : 0.f;
    const float x1 = (l >= 2) ? x[(b * L_SZ + l - 2) * D_SZ + gi] : 0.f;
    const float x0 = (l >= 3) ? x[(b * L_SZ + l - 3) * D_SZ + gi] : 0.f;
    acc = fmaf(x0, cw0, acc);
    acc = fmaf(x1, cw1, acc);
    acc = fmaf(x2, cw2, acc);
    acc = fmaf(x3, cw3, acc);
    const float uv = acc / (1.f + __expf(-acc));
    const int off = (b * L_SZ + l) * D_SZ + gi;
    u[off] = uv;
    const float dtv = dt[off];
    Tdt[ty + 8 * r][tx] = dtv;
    Tdu[ty + 8 * r][tx] = dtv * uv;
  }
  __syncthreads();
#pragma unroll
  for (int r = 0; r < 4; ++r) {
    const int il = ty + 8 * r;
    const int off = (b * D_SZ + i0 + il) * L_SZ + l0 + tx;
    dt_t[off] = Tdt[tx][il];
    dtu_t[off] = Tdu[tx][il];
  }
}

// ---------------------------------------------------------------------------
// Selective scan v6: 6-way j-split, ONE state per lane (j = 64w + lane).
// 4608 independent waves (4.5/SIMD), no barriers. dt/dtu read as uniform
// float4s from transposed rows; Cm reads fully coalesced (256 B/wave).
// Triple-buffered register pipeline pinned by fences. Value-folding
// butterfly reduction; lanes 0..7 store 8 consecutive l per chunk.
// Partials stored [w][b][i][l]; u*D applied in combine.
// ---------------------------------------------------------------------------
#define CH 8
__global__ __launch_bounds__(256, 4) void scan_kernel(
    const float* __restrict__ A_log, const float* __restrict__ dt_t,
    const float* __restrict__ dtu_t, const float* __restrict__ Bm,
    const float* __restrict__ Cm, float* __restrict__ part) {
  const int wid = ((blockIdx.x << 8) + (int)threadIdx.x) >> 6;  // 0..4607
  const int lane = threadIdx.x & 63;
  const int w = wid % 6;
  const int sid = wid / 6;
  const int b = sid / D_SZ;
  const int i = sid % D_SZ;
  const int j = w * 64 + lane;

  const float a2 = -__expf(A_log[i * S_SZ + j]) * LOG2E;
  const float bw = Bm[(b * D_SZ + i) * S_SZ + j];
  float h = 0.f;

  const float* dtp = dt_t + (b * D_SZ + i) * L_SZ;   // contiguous in l
  const float* dup = dtu_t + (b * D_SZ + i) * L_SZ;
  const float* cp = Cm + b * BLK_ELEMS + j;          // + l*D_SZ per step
  float* pp = part + ((w * B_SZ + b) * D_SZ + i) * L_SZ;

  const int sidx = ((lane & 1) << 2) | (lane & 2) | ((lane >> 2) & 1);
  const bool storer = lane < 8;

  float C0[8], D0[8], U0[8];
  float C1[8], D1[8], U1[8];
  float C2[8], D2[8], U2[8];

  auto load_chunk = [&](int c, float (&cx)[8], float (&dx)[8], float (&ux)[8]) {
    const int l0 = c * CH;
    *(float4*)&dx[0] = *(const float4*)(dtp + l0);
    *(float4*)&dx[4] = *(const float4*)(dtp + l0 + 4);
    *(float4*)&ux[0] = *(const float4*)(dup + l0);
    *(float4*)&ux[4] = *(const float4*)(dup + l0 + 4);
#pragma unroll
    for (int s = 0; s < CH; ++s) cx[s] = cp[(l0 + s) * D_SZ];
  };

  auto compute_chunk = [&](int c, const float (&cx)[8], const float (&dx)[8],
                           const float (&ux)[8]) {
    float accs[8];
#pragma unroll
    for (int s = 0; s < CH; ++s) {
      const float e = fexp2(dx[s] * a2);
      h = fmaf(e, h, bw * ux[s]);
      accs[s] = h * cx[s];
    }
    // fold 8 values into lanes (bitrev3 target), then cross-group sum
    {
      const bool s1 = (lane & 1) != 0;
#pragma unroll
      for (int q = 0; q < 4; ++q) {
        const float keep = s1 ? accs[q + 4] : accs[q];
        const float send = s1 ? accs[q] : accs[q + 4];
        accs[q] = keep + __shfl_xor(send, 1, 64);
      }
      const bool s2 = (lane & 2) != 0;
#pragma unroll
      for (int q = 0; q < 2; ++q) {
        const float keep = s2 ? accs[q + 2] : accs[q];
        const float send = s2 ? accs[q] : accs[q + 2];
        accs[q] = keep + __shfl_xor(send, 2, 64);
      }
      const bool s3 = (lane & 4) != 0;
      {
        const float keep = s3 ? accs[1] : accs[0];
        const float send = s3 ? accs[0] : accs[1];
        accs[0] = keep + __shfl_xor(send, 4, 64);
      }
    }
    float r = accs[0];
    r += __shfl_xor(r, 8, 64);
    r += __shfl_xor(r, 16, 64);
    r += __shfl_xor(r, 32, 64);
    if (storer) pp[c * CH + sidx] = r;
  };

  load_chunk(0, C0, D0, U0);
  load_chunk(1, C1, D1, U1);
  for (int it = 0; it < 16; ++it) {
    const int c = 3 * it;
    load_chunk((c + 2 < 48) ? c + 2 : 47, C2, D2, U2);
    PIPELINE_FENCE();
    compute_chunk(c, C0, D0, U0);
    load_chunk((c + 3 < 48) ? c + 3 : 47, C0, D0, U0);
    PIPELINE_FENCE();
    compute_chunk(c + 1, C1, D1, U1);
    load_chunk((c + 4 < 48) ? c + 4 : 47, C1, D1, U1);
    PIPELINE_FENCE();
    compute_chunk(c + 2, C2, D2, U2);
  }
}

// ---------------------------------------------------------------------------
// Combine + transpose: y[b,l,i] = sum_w part[w][b][i][l] + u[b,l,i]*D[i]
// ---------------------------------------------------------------------------
__global__ __launch_bounds__(256) void combine_kernel(
    const float* __restrict__ part, const float* __restrict__ u,
    const float* __restrict__ Dv, float* __restrict__ y) {
  __shared__ float T[32][33];
  const int tx = threadIdx.x;        // 0..31
  const int ty0 = threadIdx.y;       // 0..7
  const int b = blockIdx.z;
  const int i0 = blockIdx.y * 32;
  const int l0 = blockIdx.x * 32;
#pragma unroll
  for (int r = 0; r < 4; ++r) {
    const int il = ty0 + 8 * r;
    float s = 0.f;
#pragma unroll
    for (int w = 0; w < 6; ++w)
      s += part[((w * B_SZ + b) * D_SZ + i0 + il) * L_SZ + l0 + tx];
    T[il][tx] = s;
  }
  __syncthreads();
#pragma unroll
  for (int r = 0; r < 4; ++r) {
    const int ll = ty0 + 8 * r;
    const int gi = i0 + tx;
    const int off = (b * L_SZ + l0 + ll) * D_SZ + gi;
    y[off] = fmaf(u[off], Dv[gi], T[tx][ll]);
  }
}

extern "C" void kernel_launch(void* const* d_in, const int* in_sizes, int n_in,
                              void* d_out, int out_size, void* d_ws,
                              size_t ws_size, hipStream_t stream) {
  const float* x = (const float*)d_in[0];
  const float* A_log = (const float*)d_in[1];
  const float* D = (const float*)d_in[2];
  const float* dt_w = (const float*)d_in[3];
  const float* dt_b = (const float*)d_in[4];
  const float* B_w = (const float*)d_in[5];
  const float* C_w = (const float*)d_in[6];
  const float* conv_w = (const float*)d_in[7];
  const float* conv_b = (const float*)d_in[8];
  float* y = (float*)d_out;

  float* ws = (float*)d_ws;
  float* dt = ws;                     // slot 0  [b,l,i]
  float* u = ws + TOT_ELEMS;          // slot 1
  float* Bm = ws + 2 * TOT_ELEMS;     // slot 2
  float* Cm = ws + 3 * TOT_ELEMS;     // slot 3
  float* dt_t = ws + 4 * TOT_ELEMS;   // slot 4  [b,i,l]
  float* dtu_t = ws + 5 * TOT_ELEMS;  // slot 5  [b,i,l]
  float* part = ws + 6 * TOT_ELEMS;   // slots 6..11  [w][b][i][l]
  // bf16 area after the 12 f32 slots (~14.2 MB + ~2.1 MB)
  unsigned short* bfarea = (unsigned short*)(ws + 12 * TOT_ELEMS);
  unsigned short* xbf = bfarea;                 // 294912
  unsigned short* dtwbf = bfarea + 294912;      // 147456
  unsigned short* Bwbf = bfarea + 442368;       // 147456
  unsigned short* Cwbf = bfarea + 589824;       // 147456
  unsigned short* xdblbf = bfarea + 737280;     // 294912

  cvt_bf16_kernel<<<720, 256, 0, stream>>>(x, dt_w, B_w, C_w, xbf, dtwbf, Bwbf, Cwbf);
  // GEMM1: dt = softplus(x·dt_w^T + b), x_dbl(bf16) = x·B_w^T
  mfma_dual_gemm<1><<<288, 256, 0, stream>>>(xbf, dtwbf, Bwbf, dt_b, dt, xdblbf);
  // GEMM2: Bm = x_dbl·B_w^T, Cm = x_dbl·C_w^T
  mfma_dual_gemm<2><<<288, 256, 0, stream>>>(xdblbf, Bwbf, Cwbf, nullptr, Bm, Cm);
  conv_tr_kernel<<<dim3(L_SZ / 32, D_SZ / 32, B_SZ), dim3(32, 8), 0, stream>>>(
      x, conv_w, conv_b, dt, u, dt_t, dtu_t);
  scan_kernel<<<(6 * B_SZ * D_SZ) / 4, 256, 0, stream>>>(A_log, dt_t, dtu_t, Bm, Cm, part);
  combine_kernel<<<dim3(L_SZ / 32, D_SZ / 32, B_SZ), dim3(32, 8), 0, stream>>>(
      part, u, D, y);
}